// Round 1
// baseline (272.201 us; speedup 1.0000x reference)
//
#include <hip/hip_runtime.h>
#include <stdint.h>
#include <stddef.h>

// ---------------------------------------------------------------------------
// SwinBlock: rearrange -> QKV proj -> 8-head attention (L=256, D=32)
//            -> out proj -> LayerNorm -> inverse rearrange
// bf16 MFMA internal compute, fp32 in/out. MI355X gfx950.
// ---------------------------------------------------------------------------

typedef __attribute__((ext_vector_type(8))) short bf16x8;   // 8 bf16 in 4 VGPRs
typedef __attribute__((ext_vector_type(4))) float f32x4;
typedef unsigned short bf16u;

#define LOG2E 1.4426950408889634f

__device__ __forceinline__ bf16u f2b(float f) {
  uint32_t u = __float_as_uint(f);
  u += 0x7fffu + ((u >> 16) & 1u);          // round-to-nearest-even
  return (bf16u)(u >> 16);
}
__device__ __forceinline__ float b2f(bf16u s) {
  return __uint_as_float(((uint32_t)s) << 16);
}

__device__ __forceinline__ void gload_lds16(const void* g, void* l) {
  __builtin_amdgcn_global_load_lds((__attribute__((address_space(1))) void*)(g),
                                   (__attribute__((address_space(3))) void*)(l),
                                   16, 0, 0);
}

// --------------------------- weight convert fp32->bf16 ---------------------
__global__ __launch_bounds__(256) void k_convert(const float* __restrict__ s,
                                                 bf16u* __restrict__ d, int n) {
  int i = blockIdx.x * 256 + threadIdx.x;
  if (i < n) d[i] = f2b(s[i]);
}

// --------------------------- K1: rearrange x -> Tb -------------------------
// Tb[i][c], i = n*256 + l, n = b*64 + h2*8 + w2, l = h1*16 + w1
__global__ __launch_bounds__(256) void k_rearrange(const float* __restrict__ x,
                                                   bf16u* __restrict__ Tb) {
  const int bid = blockIdx.x;
  const int ct = bid & 7, hh = (bid >> 3) & 127, b = bid >> 10;
  const int c0 = ct * 32;
  const int h1 = hh >> 3, h2 = hh & 7;
  __shared__ float tile[32][129];
  for (int e = threadIdx.x; e < 4096; e += 256) {
    int cc = e >> 7, ww = e & 127;   // coalesced x reads (512B rows)
    tile[cc][ww] = x[(((size_t)(b * 256 + c0 + cc)) * 128 + hh) * 128 + ww];
  }
  __syncthreads();
  for (int e = threadIdx.x; e < 4096; e += 256) {
    int ww = e >> 5, cc = e & 31;    // contiguous-in-c writes
    int w1 = ww >> 3, w2 = ww & 7;
    int i = ((b * 64 + h2 * 8 + w2) << 8) | (h1 * 16 + w1);
    Tb[(size_t)i * 256 + c0 + cc] = f2b(tile[cc][ww]);
  }
}

// --------------------------- K2: QKV GEMM ----------------------------------
// C[i,o] = sum_k Tb[i,k]*W[o,k] + bias[o]; 128x128 tile, BK=32, 4 waves (2x2)
__global__ __launch_bounds__(256) void k_qkv(const bf16u* __restrict__ Tb,
                                             const bf16u* __restrict__ Wb,
                                             const float* __restrict__ bias,
                                             bf16u* __restrict__ Qb,
                                             bf16u* __restrict__ Kb,
                                             bf16u* __restrict__ Vb) {
  __shared__ bf16u As[128 * 32];
  __shared__ bf16u Bs[128 * 32];
  const int i0 = blockIdx.x * 128, o0 = blockIdx.y * 128;
  const int t = threadIdx.x;
  const int lane = t & 63, lo = lane & 15, hi = lane >> 4;
  const int w = t >> 6, wr = w >> 1, wc = w & 1;
  const int srow = t >> 2, schunk = (t & 3) * 8, sbase = (t & 192) * 8;
  f32x4 acc[4][4] = {};
  for (int k0 = 0; k0 < 256; k0 += 32) {
    __syncthreads();
    gload_lds16(Tb + (size_t)(i0 + srow) * 256 + k0 + schunk, As + sbase);
    gload_lds16(Tb + (size_t)(i0 + 64 + srow) * 256 + k0 + schunk, As + 2048 + sbase);
    gload_lds16(Wb + (size_t)(o0 + srow) * 256 + k0 + schunk, Bs + sbase);
    gload_lds16(Wb + (size_t)(o0 + 64 + srow) * 256 + k0 + schunk, Bs + 2048 + sbase);
    __syncthreads();
    bf16x8 af[4], bf_[4];
#pragma unroll
    for (int m = 0; m < 4; ++m)
      af[m] = *(const bf16x8*)&As[(wr * 64 + m * 16 + lo) * 32 + hi * 8];
#pragma unroll
    for (int nn = 0; nn < 4; ++nn)
      bf_[nn] = *(const bf16x8*)&Bs[(wc * 64 + nn * 16 + lo) * 32 + hi * 8];
#pragma unroll
    for (int m = 0; m < 4; ++m)
#pragma unroll
      for (int nn = 0; nn < 4; ++nn)
        acc[m][nn] = __builtin_amdgcn_mfma_f32_16x16x32_bf16(af[m], bf_[nn], acc[m][nn], 0, 0, 0);
  }
  const float qscale = 0.17677669529663687f;   // 32^-0.5
#pragma unroll
  for (int m = 0; m < 4; ++m) {
#pragma unroll
    for (int nn = 0; nn < 4; ++nn) {
      const int o = o0 + wc * 64 + nn * 16 + lo;
      const int seg = o >> 8, within = o & 255, head = within >> 5, dd = within & 31;
      bf16u* dst = seg == 0 ? Qb : (seg == 1 ? Kb : Vb);
      const float bia = bias[o];
      const float sc = (seg == 0) ? qscale : 1.0f;
#pragma unroll
      for (int r = 0; r < 4; ++r) {
        int tok = i0 + wr * 64 + m * 16 + hi * 4 + r;
        float v = (acc[m][nn][r] + bia) * sc;
        int nt = tok >> 8, ls = tok & 255;
        dst[((size_t)((nt * 8 + head) * 256 + ls)) * 32 + dd] = f2b(v);
      }
    }
  }
}

// --------------------------- K3: attention ---------------------------------
// one block per (n, head); 4 waves x 64 Q-rows; online softmax over 4 KV tiles
__global__ __launch_bounds__(256) void k_attn(const bf16u* __restrict__ Qb,
                                              const bf16u* __restrict__ Kb,
                                              const bf16u* __restrict__ Vb,
                                              bf16u* __restrict__ Ob) {
  __shared__ bf16u Ks[256 * 32];        // [kv][d]
  __shared__ bf16u Vt[32 * 264];        // [d][kv], padded row (528B, 16B-aligned)
  __shared__ bf16u Pl[4][64 * 72];      // per-wave P tile, padded row (144B)
  const int nh = blockIdx.x;
  const int n = nh >> 3, h = nh & 7;
  const bf16u* Qp = Qb + (size_t)nh * 8192;
  const bf16u* Kp = Kb + (size_t)nh * 8192;
  const bf16u* Vp = Vb + (size_t)nh * 8192;
  const int t = threadIdx.x, w = t >> 6, lane = t & 63, lo = lane & 15, hi = lane >> 4;
  const int srow = t >> 2, schunk = (t & 3) * 8, sbase = (t & 192) * 8;
#pragma unroll
  for (int j = 0; j < 4; ++j)
    gload_lds16(Kp + (size_t)(j * 64 + srow) * 32 + schunk, Ks + j * 2048 + sbase);
#pragma unroll
  for (int j = 0; j < 4; ++j) {        // V transposed into LDS
    int m = j * 64 + srow;
    bf16x8 v = *(const bf16x8*)(Vp + (size_t)m * 32 + schunk);
#pragma unroll
    for (int e = 0; e < 8; ++e) Vt[(schunk + e) * 264 + m] = (bf16u)v[e];
  }
  bf16x8 aq[4];
#pragma unroll
  for (int m = 0; m < 4; ++m)
    aq[m] = *(const bf16x8*)(Qp + (size_t)(w * 64 + m * 16 + lo) * 32 + hi * 8);
  f32x4 accO[4][2] = {};
  float rmax[4][4], rsum[4][4];
#pragma unroll
  for (int m = 0; m < 4; ++m)
#pragma unroll
    for (int r = 0; r < 4; ++r) { rmax[m][r] = -1e30f; rsum[m][r] = 0.f; }
  __syncthreads();
  for (int kt = 0; kt < 4; ++kt) {
    bf16x8 bk[4];
#pragma unroll
    for (int nn = 0; nn < 4; ++nn)
      bk[nn] = *(const bf16x8*)&Ks[(kt * 64 + nn * 16 + lo) * 32 + hi * 8];
    f32x4 s[4][4];
    const f32x4 zz = {};
#pragma unroll
    for (int m = 0; m < 4; ++m)
#pragma unroll
      for (int nn = 0; nn < 4; ++nn)
        s[m][nn] = __builtin_amdgcn_mfma_f32_16x16x32_bf16(aq[m], bk[nn], zz, 0, 0, 0);
    // online softmax per row (rows of this wave: w*64 + m*16 + hi*4 + r)
#pragma unroll
    for (int m = 0; m < 4; ++m)
#pragma unroll
      for (int r = 0; r < 4; ++r) {
        float tm = fmaxf(fmaxf(s[m][0][r], s[m][1][r]), fmaxf(s[m][2][r], s[m][3][r]));
        tm = fmaxf(tm, __shfl_xor(tm, 1));
        tm = fmaxf(tm, __shfl_xor(tm, 2));
        tm = fmaxf(tm, __shfl_xor(tm, 4));
        tm = fmaxf(tm, __shfl_xor(tm, 8));
        float om = rmax[m][r];
        float nm = fmaxf(om, tm);
        rmax[m][r] = nm;
        float corr = exp2f((om - nm) * LOG2E);
        float ts = 0.f;
#pragma unroll
        for (int nn = 0; nn < 4; ++nn) {
          float p = exp2f((s[m][nn][r] - nm) * LOG2E);
          s[m][nn][r] = p;
          ts += p;
        }
        ts += __shfl_xor(ts, 1);
        ts += __shfl_xor(ts, 2);
        ts += __shfl_xor(ts, 4);
        ts += __shfl_xor(ts, 8);
        rsum[m][r] = rsum[m][r] * corr + ts;
        accO[m][0][r] *= corr;
        accO[m][1][r] *= corr;
      }
    __syncthreads();   // prev PV reads of Pl done before overwrite
#pragma unroll
    for (int m = 0; m < 4; ++m)
#pragma unroll
      for (int nn = 0; nn < 4; ++nn)
#pragma unroll
        for (int r = 0; r < 4; ++r)
          Pl[w][(m * 16 + hi * 4 + r) * 72 + nn * 16 + lo] = f2b(s[m][nn][r]);
    __syncthreads();   // P visible before A-frag reads
#pragma unroll
    for (int kc = 0; kc < 2; ++kc) {
      bf16x8 pa[4], bv[2];
#pragma unroll
      for (int m = 0; m < 4; ++m)
        pa[m] = *(const bf16x8*)&Pl[w][(m * 16 + lo) * 72 + kc * 32 + hi * 8];
#pragma unroll
      for (int df = 0; df < 2; ++df)
        bv[df] = *(const bf16x8*)&Vt[(df * 16 + lo) * 264 + kt * 64 + kc * 32 + hi * 8];
#pragma unroll
      for (int m = 0; m < 4; ++m)
#pragma unroll
        for (int df = 0; df < 2; ++df)
          accO[m][df] = __builtin_amdgcn_mfma_f32_16x16x32_bf16(pa[m], bv[df], accO[m][df], 0, 0, 0);
    }
  }
#pragma unroll
  for (int m = 0; m < 4; ++m)
#pragma unroll
    for (int df = 0; df < 2; ++df)
#pragma unroll
      for (int r = 0; r < 4; ++r) {
        int lrow = w * 64 + m * 16 + hi * 4 + r;
        int c = h * 32 + df * 16 + lo;
        Ob[((size_t)n * 256 + lrow) * 256 + c] = f2b(accO[m][df][r] / rsum[m][r]);
      }
}

// --------------------------- K4: out proj + LayerNorm ----------------------
// 64 tokens x all 256 channels per block; LN fused in epilogue
__global__ __launch_bounds__(256) void k_out(const bf16u* __restrict__ Ob,
                                             const bf16u* __restrict__ Wb,
                                             const float* __restrict__ bias,
                                             const float* __restrict__ lnw,
                                             const float* __restrict__ lnb,
                                             bf16u* __restrict__ On) {
  __shared__ bf16u As[64 * 32];
  __shared__ bf16u Bs[256 * 32];
  __shared__ float red[64][4][2];
  const int i0 = blockIdx.x * 64;
  const int t = threadIdx.x, w = t >> 6, lane = t & 63, lo = lane & 15, hi = lane >> 4;
  const int srow = t >> 2, schunk = (t & 3) * 8, sbase = (t & 192) * 8;
  f32x4 acc[4][4] = {};
  for (int k0 = 0; k0 < 256; k0 += 32) {
    __syncthreads();
    gload_lds16(Ob + (size_t)(i0 + srow) * 256 + k0 + schunk, As + sbase);
#pragma unroll
    for (int j = 0; j < 4; ++j)
      gload_lds16(Wb + (size_t)(j * 64 + srow) * 256 + k0 + schunk, Bs + j * 2048 + sbase);
    __syncthreads();
    bf16x8 af[4], bf_[4];
#pragma unroll
    for (int m = 0; m < 4; ++m)
      af[m] = *(const bf16x8*)&As[(m * 16 + lo) * 32 + hi * 8];
#pragma unroll
    for (int nn = 0; nn < 4; ++nn)
      bf_[nn] = *(const bf16x8*)&Bs[(w * 64 + nn * 16 + lo) * 32 + hi * 8];
#pragma unroll
    for (int m = 0; m < 4; ++m)
#pragma unroll
      for (int nn = 0; nn < 4; ++nn)
        acc[m][nn] = __builtin_amdgcn_mfma_f32_16x16x32_bf16(af[m], bf_[nn], acc[m][nn], 0, 0, 0);
  }
#pragma unroll
  for (int m = 0; m < 4; ++m)
#pragma unroll
    for (int nn = 0; nn < 4; ++nn) {
      float bia = bias[w * 64 + nn * 16 + lo];
#pragma unroll
      for (int r = 0; r < 4; ++r) acc[m][nn][r] += bia;
    }
#pragma unroll
  for (int m = 0; m < 4; ++m)
#pragma unroll
    for (int r = 0; r < 4; ++r) {
      float sv = acc[m][0][r] + acc[m][1][r] + acc[m][2][r] + acc[m][3][r];
      float sq = acc[m][0][r] * acc[m][0][r] + acc[m][1][r] * acc[m][1][r] +
                 acc[m][2][r] * acc[m][2][r] + acc[m][3][r] * acc[m][3][r];
      sv += __shfl_xor(sv, 1); sq += __shfl_xor(sq, 1);
      sv += __shfl_xor(sv, 2); sq += __shfl_xor(sq, 2);
      sv += __shfl_xor(sv, 4); sq += __shfl_xor(sq, 4);
      sv += __shfl_xor(sv, 8); sq += __shfl_xor(sq, 8);
      if (lo == 0) {
        red[m * 16 + hi * 4 + r][w][0] = sv;
        red[m * 16 + hi * 4 + r][w][1] = sq;
      }
    }
  __syncthreads();
#pragma unroll
  for (int m = 0; m < 4; ++m)
#pragma unroll
    for (int r = 0; r < 4; ++r) {
      int row = m * 16 + hi * 4 + r;
      float S  = red[row][0][0] + red[row][1][0] + red[row][2][0] + red[row][3][0];
      float Q2 = red[row][0][1] + red[row][1][1] + red[row][2][1] + red[row][3][1];
      float mu = S * 0.00390625f;
      float var = Q2 * 0.00390625f - mu * mu;
      float rstd = rsqrtf(var + 1e-5f);
#pragma unroll
      for (int nn = 0; nn < 4; ++nn) {
        int oc = w * 64 + nn * 16 + lo;
        float o = (acc[m][nn][r] - mu) * rstd * lnw[oc] + lnb[oc];
        On[(size_t)(i0 + row) * 256 + oc] = f2b(o);
      }
    }
}

// --------------------------- K5: inverse rearrange -------------------------
__global__ __launch_bounds__(256) void k_unrearrange(const bf16u* __restrict__ On,
                                                     float* __restrict__ y) {
  const int bid = blockIdx.x;
  const int ct = bid & 7, hh = (bid >> 3) & 127, b = bid >> 10;
  const int c0 = ct * 32;
  const int h1 = hh >> 3, h2 = hh & 7;
  __shared__ float tile[32][129];
  for (int e = threadIdx.x; e < 4096; e += 256) {
    int ww = e >> 5, cc = e & 31;
    int w1 = ww >> 3, w2 = ww & 7;
    int i = ((b * 64 + h2 * 8 + w2) << 8) | (h1 * 16 + w1);
    tile[cc][ww] = b2f(On[(size_t)i * 256 + c0 + cc]);
  }
  __syncthreads();
  for (int e = threadIdx.x; e < 4096; e += 256) {
    int cc = e >> 7, ww = e & 127;
    y[(((size_t)(b * 256 + c0 + cc)) * 128 + hh) * 128 + ww] = tile[cc][ww];
  }
}

// --------------------------- launch ----------------------------------------
extern "C" void kernel_launch(void* const* d_in, const int* in_sizes, int n_in,
                              void* d_out, int out_size, void* d_ws, size_t ws_size,
                              hipStream_t stream) {
  const float* x     = (const float*)d_in[0];
  const float* w_qkv = (const float*)d_in[1];
  const float* b_qkv = (const float*)d_in[2];
  const float* w_out = (const float*)d_in[3];
  const float* b_out = (const float*)d_in[4];
  const float* ln_w  = (const float*)d_in[5];
  const float* ln_b  = (const float*)d_in[6];
  float* y = (float*)d_out;

  const size_t SEG = 33554432;   // 16.7M bf16 elements = 32 MiB
  char* ws = (char*)d_ws;
  if (ws_size < 5 * SEG + 768 * 256 * 2 + 256 * 256 * 2) return;  // diagnostic fail
  bf16u* Tb = (bf16u*)(ws);                 // rearranged tokens; reused as On
  bf16u* Qb = (bf16u*)(ws + SEG);
  bf16u* Kb = (bf16u*)(ws + 2 * SEG);
  bf16u* Vb = (bf16u*)(ws + 3 * SEG);
  bf16u* Ob = (bf16u*)(ws + 4 * SEG);
  bf16u* Wqkvb = (bf16u*)(ws + 5 * SEG);
  bf16u* Woutb = (bf16u*)(ws + 5 * SEG + 768 * 256 * 2);
  bf16u* On = Tb;

  k_convert<<<768, 256, 0, stream>>>(w_qkv, Wqkvb, 768 * 256);
  k_convert<<<256, 256, 0, stream>>>(w_out, Woutb, 256 * 256);
  k_rearrange<<<4096, 256, 0, stream>>>(x, Tb);
  k_qkv<<<dim3(512, 6), 256, 0, stream>>>(Tb, Wqkvb, b_qkv, Qb, Kb, Vb);
  k_attn<<<2048, 256, 0, stream>>>(Qb, Kb, Vb, Ob);
  k_out<<<1024, 256, 0, stream>>>(Ob, Woutb, b_out, ln_w, ln_b, On);
  k_unrearrange<<<4096, 256, 0, stream>>>(On, y);
}

// Round 2
// 208.409 us; speedup vs baseline: 1.3061x; 1.3061x over previous
//
#include <hip/hip_runtime.h>
#include <stdint.h>
#include <stddef.h>

// ---------------------------------------------------------------------------
// SwinBlock: rearrange -> QKV proj -> 8-head attention (L=256, D=32)
//            -> out proj -> LayerNorm -> inverse rearrange
// bf16 MFMA internal compute, fp32 in/out. MI355X gfx950.
// R2: k_attn rewritten -- swapped QK^T (32x32x16), in-register softmax,
//     cvt_pk+permlane32_swap P repack, defer-max, no LDS, no barriers.
// ---------------------------------------------------------------------------

typedef __attribute__((ext_vector_type(8))) short bf16x8;   // 8 bf16 in 4 VGPRs
typedef __attribute__((ext_vector_type(4))) float f32x4;
typedef __attribute__((ext_vector_type(16))) float f32x16;
typedef __attribute__((ext_vector_type(4))) unsigned u32x4;
typedef unsigned short bf16u;

#define LOG2E 1.4426950408889634f
#define MFMA32(a, b, c) __builtin_amdgcn_mfma_f32_32x32x16_bf16(a, b, c, 0, 0, 0)

__device__ __forceinline__ bf16u f2b(float f) {
  uint32_t u = __float_as_uint(f);
  u += 0x7fffu + ((u >> 16) & 1u);          // round-to-nearest-even
  return (bf16u)(u >> 16);
}
__device__ __forceinline__ float b2f(bf16u s) {
  return __uint_as_float(((uint32_t)s) << 16);
}

__device__ __forceinline__ void gload_lds16(const void* g, void* l) {
  __builtin_amdgcn_global_load_lds((__attribute__((address_space(1))) void*)(g),
                                   (__attribute__((address_space(3))) void*)(l),
                                   16, 0, 0);
}

// pack 2 f32 -> u32 of 2 bf16 (low = a, high = b)
__device__ __forceinline__ unsigned cvtpk(float a, float b) {
  unsigned r;
  asm("v_cvt_pk_bf16_f32 %0, %1, %2" : "=v"(r) : "v"(a), "v"(b));
  return r;
}

// exchange upper-half lanes of a with lower-half lanes of b (lane^32 pairing)
__device__ __forceinline__ void swap32(unsigned a, unsigned b, bool hi,
                                       unsigned& x, unsigned& y) {
#if __has_builtin(__builtin_amdgcn_permlane32_swap)
  typedef __attribute__((ext_vector_type(2))) unsigned uint2v;
  uint2v r = __builtin_amdgcn_permlane32_swap(a, b, false, false);
  x = r.x;   // lanes0-31: a ; lanes32-63: b from lane-32
  y = r.y;   // lanes0-31: a from lane+32 ; lanes32-63: b
#else
  unsigned as = (unsigned)__shfl_xor((int)a, 32);
  unsigned bs = (unsigned)__shfl_xor((int)b, 32);
  x = hi ? bs : a;
  y = hi ? b : as;
#endif
}

// --------------------------- weight convert fp32->bf16 ---------------------
__global__ __launch_bounds__(256) void k_convert(const float* __restrict__ s,
                                                 bf16u* __restrict__ d, int n) {
  int i = blockIdx.x * 256 + threadIdx.x;
  if (i < n) d[i] = f2b(s[i]);
}

// --------------------------- K1: rearrange x -> Tb -------------------------
// Tb[i][c], i = n*256 + l, n = b*64 + h2*8 + w2, l = h1*16 + w1
__global__ __launch_bounds__(256) void k_rearrange(const float* __restrict__ x,
                                                   bf16u* __restrict__ Tb) {
  const int bid = blockIdx.x;
  const int ct = bid & 7, hh = (bid >> 3) & 127, b = bid >> 10;
  const int c0 = ct * 32;
  const int h1 = hh >> 3, h2 = hh & 7;
  __shared__ float tile[32][129];
  for (int e = threadIdx.x; e < 4096; e += 256) {
    int cc = e >> 7, ww = e & 127;   // coalesced x reads (512B rows)
    tile[cc][ww] = x[(((size_t)(b * 256 + c0 + cc)) * 128 + hh) * 128 + ww];
  }
  __syncthreads();
  for (int e = threadIdx.x; e < 4096; e += 256) {
    int ww = e >> 5, cc = e & 31;    // contiguous-in-c writes
    int w1 = ww >> 3, w2 = ww & 7;
    int i = ((b * 64 + h2 * 8 + w2) << 8) | (h1 * 16 + w1);
    Tb[(size_t)i * 256 + c0 + cc] = f2b(tile[cc][ww]);
  }
}

// --------------------------- K2: QKV GEMM ----------------------------------
// C[i,o] = sum_k Tb[i,k]*W[o,k] + bias[o]; 128x128 tile, BK=32, 4 waves (2x2)
__global__ __launch_bounds__(256) void k_qkv(const bf16u* __restrict__ Tb,
                                             const bf16u* __restrict__ Wb,
                                             const float* __restrict__ bias,
                                             bf16u* __restrict__ Qb,
                                             bf16u* __restrict__ Kb,
                                             bf16u* __restrict__ Vb) {
  __shared__ bf16u As[128 * 32];
  __shared__ bf16u Bs[128 * 32];
  const int i0 = blockIdx.x * 128, o0 = blockIdx.y * 128;
  const int t = threadIdx.x;
  const int lane = t & 63, lo = lane & 15, hi = lane >> 4;
  const int w = t >> 6, wr = w >> 1, wc = w & 1;
  const int srow = t >> 2, schunk = (t & 3) * 8, sbase = (t & 192) * 8;
  f32x4 acc[4][4] = {};
  for (int k0 = 0; k0 < 256; k0 += 32) {
    __syncthreads();
    gload_lds16(Tb + (size_t)(i0 + srow) * 256 + k0 + schunk, As + sbase);
    gload_lds16(Tb + (size_t)(i0 + 64 + srow) * 256 + k0 + schunk, As + 2048 + sbase);
    gload_lds16(Wb + (size_t)(o0 + srow) * 256 + k0 + schunk, Bs + sbase);
    gload_lds16(Wb + (size_t)(o0 + 64 + srow) * 256 + k0 + schunk, Bs + 2048 + sbase);
    __syncthreads();
    bf16x8 af[4], bf_[4];
#pragma unroll
    for (int m = 0; m < 4; ++m)
      af[m] = *(const bf16x8*)&As[(wr * 64 + m * 16 + lo) * 32 + hi * 8];
#pragma unroll
    for (int nn = 0; nn < 4; ++nn)
      bf_[nn] = *(const bf16x8*)&Bs[(wc * 64 + nn * 16 + lo) * 32 + hi * 8];
#pragma unroll
    for (int m = 0; m < 4; ++m)
#pragma unroll
      for (int nn = 0; nn < 4; ++nn)
        acc[m][nn] = __builtin_amdgcn_mfma_f32_16x16x32_bf16(af[m], bf_[nn], acc[m][nn], 0, 0, 0);
  }
  const float qscale = 0.17677669529663687f;   // 32^-0.5
#pragma unroll
  for (int m = 0; m < 4; ++m) {
#pragma unroll
    for (int nn = 0; nn < 4; ++nn) {
      const int o = o0 + wc * 64 + nn * 16 + lo;
      const int seg = o >> 8, within = o & 255, head = within >> 5, dd = within & 31;
      bf16u* dst = seg == 0 ? Qb : (seg == 1 ? Kb : Vb);
      const float bia = bias[o];
      const float sc = (seg == 0) ? qscale : 1.0f;
#pragma unroll
      for (int r = 0; r < 4; ++r) {
        int tok = i0 + wr * 64 + m * 16 + hi * 4 + r;
        float v = (acc[m][nn][r] + bia) * sc;
        int nt = tok >> 8, ls = tok & 255;
        dst[((size_t)((nt * 8 + head) * 256 + ls)) * 32 + dd] = f2b(v);
      }
    }
  }
}

// --------------------------- K3: attention (v2) ----------------------------
// one block per (n,head); 4 independent waves x 64 q-rows (2 subtiles of 32).
// Swapped QK^T: S^T[kv][q] = mfma(K, Q^T) -> lane holds P-run for q=lane&31.
// In-register online softmax (defer-max THR=8), cvt_pk + permlane32_swap
// repack to PV A-frag. V B-frags via per-lane scalar loads. No LDS.
__global__ __launch_bounds__(256) void k_attn(const bf16u* __restrict__ Qb,
                                              const bf16u* __restrict__ Kb,
                                              const bf16u* __restrict__ Vb,
                                              bf16u* __restrict__ Ob) {
  const int nh = blockIdx.x;
  const int n = nh >> 3, h = nh & 7;
  const bf16u* Qp = Qb + (size_t)nh * 8192;
  const bf16u* Kp = Kb + (size_t)nh * 8192;
  const bf16u* Vp = Vb + (size_t)nh * 8192;
  const int t = threadIdx.x, w = t >> 6, lane = t & 63;
  const int l31 = lane & 31;
  const bool hi5 = (lane & 32) != 0;

  // Q fragments: B-operand of QK^T.  B[k=d][col=q] = Q[q][d]
  bf16x8 qf[2][2];
#pragma unroll
  for (int qs = 0; qs < 2; ++qs)
#pragma unroll
    for (int dh = 0; dh < 2; ++dh)
      qf[qs][dh] = *(const bf16x8*)(Qp + (size_t)(w * 64 + qs * 32 + l31) * 32 +
                                    dh * 16 + (hi5 ? 8 : 0));

  f32x16 accO[2] = {};
  float m[2] = {-3e38f, -3e38f}, rsum[2] = {0.f, 0.f};

  for (int kt = 0; kt < 8; ++kt) {
    const int kvb = kt * 32;
    // K fragments: A-operand.  A[row=kv][k=d]
    const bf16u* kp = Kp + (size_t)(kvb + l31) * 32 + (hi5 ? 8 : 0);
    bf16x8 kf0 = *(const bf16x8*)(kp);
    bf16x8 kf1 = *(const bf16x8*)(kp + 16);
    // V fragments: B-operand of PV.  B[k=kv][col=d] -> per-lane scalar loads
    const bf16u* vp0 = Vp + (size_t)(kvb + (hi5 ? 8 : 0)) * 32 + l31;
    u32x4 va, vb;
#pragma unroll
    for (int j = 0; j < 4; ++j)
      va[j] = (unsigned)vp0[(2 * j) * 32] | ((unsigned)vp0[(2 * j + 1) * 32] << 16);
    const bf16u* vp1 = vp0 + 16 * 32;
#pragma unroll
    for (int j = 0; j < 4; ++j)
      vb[j] = (unsigned)vp1[(2 * j) * 32] | ((unsigned)vp1[(2 * j + 1) * 32] << 16);
    bf16x8 vf0 = __builtin_bit_cast(bf16x8, va);
    bf16x8 vf1 = __builtin_bit_cast(bf16x8, vb);

#pragma unroll
    for (int qs = 0; qs < 2; ++qs) {
      f32x16 s = {};
      s = MFMA32(kf0, qf[qs][0], s);
      s = MFMA32(kf1, qf[qs][1], s);
      // --- online softmax for q = l31 (state duplicated across lane^32) ---
      float tm = s[0];
#pragma unroll
      for (int r = 1; r < 16; ++r) tm = fmaxf(tm, s[r]);
      tm = fmaxf(tm, __shfl_xor(tm, 32));
      if (__ballot(tm > m[qs] + 8.0f)) {       // defer-max: rarely taken
        float nm = fmaxf(m[qs], tm);
        float corr = exp2f((m[qs] - nm) * LOG2E);
        m[qs] = nm;
        rsum[qs] *= corr;
#pragma unroll
        for (int r = 0; r < 16; ++r) {
          // accO row q = (r&3)+8*(r>>2)+4*hi5 ; fetch that q's corr in-half
          int src = (lane & 32) | ((r & 3) + 8 * (r >> 2) + ((lane & 32) >> 3));
          accO[qs][r] *= __shfl(corr, src);
        }
      }
      float mL = m[qs] * LOG2E;
      float p[16];
      float ts = 0.f;
#pragma unroll
      for (int r = 0; r < 16; ++r) {
        p[r] = exp2f(fmaf(s[r], LOG2E, -mL));
        ts += p[r];
      }
      ts += __shfl_xor(ts, 32);
      rsum[qs] += ts;
      // --- pack P to bf16 and redistribute to PV A-fragment layout ---
      unsigned pk0 = cvtpk(p[0], p[1]),  pk1 = cvtpk(p[2], p[3]);
      unsigned pk2 = cvtpk(p[4], p[5]),  pk3 = cvtpk(p[6], p[7]);
      unsigned pk4 = cvtpk(p[8], p[9]),  pk5 = cvtpk(p[10], p[11]);
      unsigned pk6 = cvtpk(p[12], p[13]), pk7 = cvtpk(p[14], p[15]);
      unsigned x0, x1, x2, x3, y0, y1, y2, y3;
      swap32(pk0, pk2, hi5, x0, x2);
      swap32(pk1, pk3, hi5, x1, x3);
      swap32(pk4, pk6, hi5, y0, y2);
      swap32(pk5, pk7, hi5, y1, y3);
      u32x4 pa0 = {x0, x1, x2, x3};
      u32x4 pa1 = {y0, y1, y2, y3};
      accO[qs] = MFMA32(__builtin_bit_cast(bf16x8, pa0), vf0, accO[qs]);
      accO[qs] = MFMA32(__builtin_bit_cast(bf16x8, pa1), vf1, accO[qs]);
    }
  }
  // --- epilogue: normalize rows, write O[token][h*32+d] ---
#pragma unroll
  for (int qs = 0; qs < 2; ++qs) {
    float rn = 1.0f / rsum[qs];
#pragma unroll
    for (int r = 0; r < 16; ++r) {
      int row = (r & 3) + 8 * (r >> 2) + ((lane & 32) >> 3);
      float c = __shfl(rn, (lane & 32) | row);
      float o = accO[qs][r] * c;
      Ob[((size_t)(n * 256 + w * 64 + qs * 32 + row)) * 256 + h * 32 + l31] = f2b(o);
    }
  }
}

// --------------------------- K4: out proj + LayerNorm ----------------------
// 64 tokens x all 256 channels per block; LN fused in epilogue
__global__ __launch_bounds__(256) void k_out(const bf16u* __restrict__ Ob,
                                             const bf16u* __restrict__ Wb,
                                             const float* __restrict__ bias,
                                             const float* __restrict__ lnw,
                                             const float* __restrict__ lnb,
                                             bf16u* __restrict__ On) {
  __shared__ bf16u As[64 * 32];
  __shared__ bf16u Bs[256 * 32];
  __shared__ float red[64][4][2];
  const int i0 = blockIdx.x * 64;
  const int t = threadIdx.x, w = t >> 6, lane = t & 63, lo = lane & 15, hi = lane >> 4;
  const int srow = t >> 2, schunk = (t & 3) * 8, sbase = (t & 192) * 8;
  f32x4 acc[4][4] = {};
  for (int k0 = 0; k0 < 256; k0 += 32) {
    __syncthreads();
    gload_lds16(Ob + (size_t)(i0 + srow) * 256 + k0 + schunk, As + sbase);
#pragma unroll
    for (int j = 0; j < 4; ++j)
      gload_lds16(Wb + (size_t)(j * 64 + srow) * 256 + k0 + schunk, Bs + j * 2048 + sbase);
    __syncthreads();
    bf16x8 af[4], bf_[4];
#pragma unroll
    for (int m = 0; m < 4; ++m)
      af[m] = *(const bf16x8*)&As[(m * 16 + lo) * 32 + hi * 8];
#pragma unroll
    for (int nn = 0; nn < 4; ++nn)
      bf_[nn] = *(const bf16x8*)&Bs[(w * 64 + nn * 16 + lo) * 32 + hi * 8];
#pragma unroll
    for (int m = 0; m < 4; ++m)
#pragma unroll
      for (int nn = 0; nn < 4; ++nn)
        acc[m][nn] = __builtin_amdgcn_mfma_f32_16x16x32_bf16(af[m], bf_[nn], acc[m][nn], 0, 0, 0);
  }
#pragma unroll
  for (int m = 0; m < 4; ++m)
#pragma unroll
    for (int nn = 0; nn < 4; ++nn) {
      float bia = bias[w * 64 + nn * 16 + lo];
#pragma unroll
      for (int r = 0; r < 4; ++r) acc[m][nn][r] += bia;
    }
#pragma unroll
  for (int m = 0; m < 4; ++m)
#pragma unroll
    for (int r = 0; r < 4; ++r) {
      float sv = acc[m][0][r] + acc[m][1][r] + acc[m][2][r] + acc[m][3][r];
      float sq = acc[m][0][r] * acc[m][0][r] + acc[m][1][r] * acc[m][1][r] +
                 acc[m][2][r] * acc[m][2][r] + acc[m][3][r] * acc[m][3][r];
      sv += __shfl_xor(sv, 1); sq += __shfl_xor(sq, 1);
      sv += __shfl_xor(sv, 2); sq += __shfl_xor(sq, 2);
      sv += __shfl_xor(sv, 4); sq += __shfl_xor(sq, 4);
      sv += __shfl_xor(sv, 8); sq += __shfl_xor(sq, 8);
      if (lo == 0) {
        red[m * 16 + hi * 4 + r][w][0] = sv;
        red[m * 16 + hi * 4 + r][w][1] = sq;
      }
    }
  __syncthreads();
#pragma unroll
  for (int m = 0; m < 4; ++m)
#pragma unroll
    for (int r = 0; r < 4; ++r) {
      int row = m * 16 + hi * 4 + r;
      float S  = red[row][0][0] + red[row][1][0] + red[row][2][0] + red[row][3][0];
      float Q2 = red[row][0][1] + red[row][1][1] + red[row][2][1] + red[row][3][1];
      float mu = S * 0.00390625f;
      float var = Q2 * 0.00390625f - mu * mu;
      float rstd = rsqrtf(var + 1e-5f);
#pragma unroll
      for (int nn = 0; nn < 4; ++nn) {
        int oc = w * 64 + nn * 16 + lo;
        float o = (acc[m][nn][r] - mu) * rstd * lnw[oc] + lnb[oc];
        On[(size_t)(i0 + row) * 256 + oc] = f2b(o);
      }
    }
}

// --------------------------- K5: inverse rearrange -------------------------
__global__ __launch_bounds__(256) void k_unrearrange(const bf16u* __restrict__ On,
                                                     float* __restrict__ y) {
  const int bid = blockIdx.x;
  const int ct = bid & 7, hh = (bid >> 3) & 127, b = bid >> 10;
  const int c0 = ct * 32;
  const int h1 = hh >> 3, h2 = hh & 7;
  __shared__ float tile[32][129];
  for (int e = threadIdx.x; e < 4096; e += 256) {
    int ww = e >> 5, cc = e & 31;
    int w1 = ww >> 3, w2 = ww & 7;
    int i = ((b * 64 + h2 * 8 + w2) << 8) | (h1 * 16 + w1);
    tile[cc][ww] = b2f(On[(size_t)i * 256 + c0 + cc]);
  }
  __syncthreads();
  for (int e = threadIdx.x; e < 4096; e += 256) {
    int cc = e >> 7, ww = e & 127;
    y[(((size_t)(b * 256 + c0 + cc)) * 128 + hh) * 128 + ww] = tile[cc][ww];
  }
}

// --------------------------- launch ----------------------------------------
extern "C" void kernel_launch(void* const* d_in, const int* in_sizes, int n_in,
                              void* d_out, int out_size, void* d_ws, size_t ws_size,
                              hipStream_t stream) {
  const float* x     = (const float*)d_in[0];
  const float* w_qkv = (const float*)d_in[1];
  const float* b_qkv = (const float*)d_in[2];
  const float* w_out = (const float*)d_in[3];
  const float* b_out = (const float*)d_in[4];
  const float* ln_w  = (const float*)d_in[5];
  const float* ln_b  = (const float*)d_in[6];
  float* y = (float*)d_out;

  const size_t SEG = 33554432;   // 16.7M bf16 elements = 32 MiB
  char* ws = (char*)d_ws;
  if (ws_size < 5 * SEG + 768 * 256 * 2 + 256 * 256 * 2) return;  // diagnostic fail
  bf16u* Tb = (bf16u*)(ws);                 // rearranged tokens; reused as On
  bf16u* Qb = (bf16u*)(ws + SEG);
  bf16u* Kb = (bf16u*)(ws + 2 * SEG);
  bf16u* Vb = (bf16u*)(ws + 3 * SEG);
  bf16u* Ob = (bf16u*)(ws + 4 * SEG);
  bf16u* Wqkvb = (bf16u*)(ws + 5 * SEG);
  bf16u* Woutb = (bf16u*)(ws + 5 * SEG + 768 * 256 * 2);
  bf16u* On = Tb;

  k_convert<<<768, 256, 0, stream>>>(w_qkv, Wqkvb, 768 * 256);
  k_convert<<<256, 256, 0, stream>>>(w_out, Woutb, 256 * 256);
  k_rearrange<<<4096, 256, 0, stream>>>(x, Tb);
  k_qkv<<<dim3(512, 6), 256, 0, stream>>>(Tb, Wqkvb, b_qkv, Qb, Kb, Vb);
  k_attn<<<2048, 256, 0, stream>>>(Qb, Kb, Vb, Ob);
  k_out<<<1024, 256, 0, stream>>>(Ob, Woutb, b_out, ln_w, ln_b, On);
  k_unrearrange<<<4096, 256, 0, stream>>>(On, y);
}